// Round 1
// baseline (479.200 us; speedup 1.0000x reference)
//
#include <hip/hip_runtime.h>

// Attention: qkv = x @ W^T + b ; causal MHA ; B=4 T=2048 C=1024 H=16 D=64
// Strategy: bf16 MFMA everywhere (2% absmax budget). V stored transposed by the
// GEMM epilogue so PV fragment reads are contiguous.
// Workspace layout (needs >= 73.4 MB):
//   xb  @ 0        : x  in bf16 [8192][1024]                (16 MB)
//   wb  @ 16 MB    : W  in bf16 [3072][1024]                ( 6 MB)
//   qb  @ 22 MB    : q  in bf16 [B][H][T][D], pre-scaled 1/8 (16 MB)
//   kb  @ 38 MB    : k  in bf16 [B][H][T][D]                (16 MB)
//   vtb @ 54 MB    : v^T in bf16 [B][H][D][T]               (16 MB)

typedef __attribute__((ext_vector_type(8))) short short8;
typedef __attribute__((ext_vector_type(4))) float f32x4;

#define LOG2E 1.4426950408889634f

__device__ __forceinline__ unsigned short f2bf(float f) {
  unsigned int u = __float_as_uint(f);
  u += 0x7fffu + ((u >> 16) & 1u);
  return (unsigned short)(u >> 16);
}

// ---------------- fp32 -> bf16 bulk convert ----------------
__global__ __launch_bounds__(256) void cvt_bf16(const float* __restrict__ in,
                                                unsigned short* __restrict__ out,
                                                int n8) {
  int i = blockIdx.x * 256 + threadIdx.x;
  if (i >= n8) return;
  const float4* p = (const float4*)in + (size_t)i * 2;
  float4 a = p[0], b = p[1];
  uint4 o;
  o.x = (unsigned)f2bf(a.x) | ((unsigned)f2bf(a.y) << 16);
  o.y = (unsigned)f2bf(a.z) | ((unsigned)f2bf(a.w) << 16);
  o.z = (unsigned)f2bf(b.x) | ((unsigned)f2bf(b.y) << 16);
  o.w = (unsigned)f2bf(b.z) | ((unsigned)f2bf(b.w) << 16);
  *(uint4*)(out + (size_t)i * 8) = o;
}

// ---------------- QKV projection GEMM ----------------
// C[m][o] = sum_k x[m][k] * W[o][k] + b[o]; M=8192 N=3072 K=1024
// 128x128 block tile, BK=32, 4 waves (2x2), each wave 64x64 via 4x4 16x16x32 MFMA.
__global__ __launch_bounds__(256) void qkv_gemm(const unsigned short* __restrict__ A,
                                                const unsigned short* __restrict__ Bw,
                                                const float* __restrict__ bias,
                                                unsigned short* __restrict__ qb,
                                                unsigned short* __restrict__ kb,
                                                unsigned short* __restrict__ vtb) {
  const int K = 1024;
  __shared__ unsigned short As[128 * 40];  // +8 pad: conflict-free b128 reads
  __shared__ unsigned short Bs[128 * 40];
  int tid = threadIdx.x;
  int wave = tid >> 6, lane = tid & 63;
  int q4 = lane >> 4, l16 = lane & 15;
  int bm = blockIdx.x, bn = blockIdx.y;
  int wm = (wave & 1) * 64, wn = (wave >> 1) * 64;

  f32x4 zero = {0.f, 0.f, 0.f, 0.f};
  f32x4 acc[4][4];
#pragma unroll
  for (int i = 0; i < 4; ++i)
#pragma unroll
    for (int j = 0; j < 4; ++j) acc[i][j] = zero;

  const unsigned short* Arow = A + (size_t)(bm * 128) * K;
  const unsigned short* Brow = Bw + (size_t)(bn * 128) * K;

  for (int kt = 0; kt < 32; ++kt) {
    __syncthreads();
    int kbase = kt * 32;
#pragma unroll
    for (int it = 0; it < 2; ++it) {
      int cn = it * 256 + tid;
      int row = cn >> 2, cc = cn & 3;
      uint4 va = *(const uint4*)(Arow + (size_t)row * K + kbase + cc * 8);
      *(uint4*)(&As[row * 40 + cc * 8]) = va;
      uint4 vb = *(const uint4*)(Brow + (size_t)row * K + kbase + cc * 8);
      *(uint4*)(&Bs[row * 40 + cc * 8]) = vb;
    }
    __syncthreads();
    short8 af[4], bf[4];
#pragma unroll
    for (int i = 0; i < 4; ++i)
      af[i] = *(const short8*)(&As[(wm + i * 16 + l16) * 40 + q4 * 8]);
#pragma unroll
    for (int j = 0; j < 4; ++j)
      bf[j] = *(const short8*)(&Bs[(wn + j * 16 + l16) * 40 + q4 * 8]);
#pragma unroll
    for (int i = 0; i < 4; ++i)
#pragma unroll
      for (int j = 0; j < 4; ++j)
        acc[i][j] = __builtin_amdgcn_mfma_f32_16x16x32_bf16(af[i], bf[j], acc[i][j], 0, 0, 0);
  }

  // Epilogue: +bias, scatter to q (scaled 1/8), k, or v^T.
  // C/D layout: col = lane&15, row = q4*4 + reg   [measured m89/m91]
  int rowbase = bm * 128 + wm;
  int colbase = bn * 128 + wn;
#pragma unroll
  for (int j = 0; j < 4; ++j) {
    int o = colbase + j * 16 + l16;
    float bv = bias[o];
#pragma unroll
    for (int i = 0; i < 4; ++i) {
      int r0 = rowbase + i * 16 + q4 * 4;  // global row (b*2048+t), mult of 4
      if (o < 1024) {
        int h = o >> 6, d = o & 63;
#pragma unroll
        for (int r = 0; r < 4; ++r) {
          int m = r0 + r;
          int b = m >> 11, t = m & 2047;
          qb[((((size_t)b * 16 + h) * 2048 + t) << 6) + d] =
              f2bf((acc[i][j][r] + bv) * 0.125f);
        }
      } else if (o < 2048) {
        int o2 = o - 1024;
        int h = o2 >> 6, d = o2 & 63;
#pragma unroll
        for (int r = 0; r < 4; ++r) {
          int m = r0 + r;
          int b = m >> 11, t = m & 2047;
          kb[((((size_t)b * 16 + h) * 2048 + t) << 6) + d] = f2bf(acc[i][j][r] + bv);
        }
      } else {
        int o3 = o - 2048;
        int h = o3 >> 6, d = o3 & 63;
        int b = r0 >> 11, t = r0 & 2047;  // 4 consecutive t share b
        ushort4 pk;
        pk.x = f2bf(acc[i][j][0] + bv);
        pk.y = f2bf(acc[i][j][1] + bv);
        pk.z = f2bf(acc[i][j][2] + bv);
        pk.w = f2bf(acc[i][j][3] + bv);
        *(ushort4*)(&vtb[((((size_t)b * 16 + h) * 64 + d) << 11) + t]) = pk;
      }
    }
  }
}

// ---------------- Flash attention ----------------
// Grid (qt=16, bh=64). 256 thr. Q-tile 128 (wave owns 32 rows), K-tile 128.
__global__ __launch_bounds__(256) void flash_attn(const unsigned short* __restrict__ qb,
                                                  const unsigned short* __restrict__ kb,
                                                  const unsigned short* __restrict__ vtb,
                                                  float* __restrict__ out) {
  __shared__ unsigned short Qs[128 * 72];   // [t][d], +8 pad
  __shared__ unsigned short Ks[128 * 72];   // [s][d], +8 pad
  __shared__ unsigned short Vts[64 * 136];  // [d][s], +8 pad
  __shared__ unsigned short Ps[4][32 * 40]; // per-wave P chunk [t][s], +8 pad

  int tid = threadIdx.x;
  int wave = tid >> 6, lane = tid & 63;
  int q4 = lane >> 4, l16 = lane & 15;
  int qt = blockIdx.x, bh = blockIdx.y;

  const unsigned short* Qg = qb + (size_t)bh * 2048 * 64;
  const unsigned short* Kg = kb + (size_t)bh * 2048 * 64;
  const unsigned short* Vg = vtb + (size_t)bh * 64 * 2048;

  // stage Q tile [128][64]
#pragma unroll
  for (int it = 0; it < 4; ++it) {
    int cn = it * 256 + tid;
    int row = cn >> 3, cc = cn & 7;
    *(uint4*)(&Qs[row * 72 + cc * 8]) =
        *(const uint4*)(Qg + (size_t)(qt * 128 + row) * 64 + cc * 8);
  }

  f32x4 zero = {0.f, 0.f, 0.f, 0.f};
  f32x4 o_acc[2][4];
  float m_st[2][4], l_st[2][4];
#pragma unroll
  for (int mi = 0; mi < 2; ++mi) {
#pragma unroll
    for (int nd = 0; nd < 4; ++nd) o_acc[mi][nd] = zero;
#pragma unroll
    for (int r = 0; r < 4; ++r) { m_st[mi][r] = -3.0e38f; l_st[mi][r] = 0.f; }
  }

  for (int st = 0; st <= qt; ++st) {
    __syncthreads();  // prior iter's frag reads done
    // stage K tile [128][64]
#pragma unroll
    for (int it = 0; it < 4; ++it) {
      int cn = it * 256 + tid;
      int row = cn >> 3, cc = cn & 7;
      *(uint4*)(&Ks[row * 72 + cc * 8]) =
          *(const uint4*)(Kg + (size_t)(st * 128 + row) * 64 + cc * 8);
    }
    // stage V^T tile [64][128]
#pragma unroll
    for (int it = 0; it < 4; ++it) {
      int cn = it * 256 + tid;
      int row = cn >> 4, cc = cn & 15;
      *(uint4*)(&Vts[row * 136 + cc * 8]) =
          *(const uint4*)(Vg + (size_t)row * 2048 + st * 128 + cc * 8);
    }
    __syncthreads();

    // S = Q K^T (q pre-scaled by 1/8): acc [2 mt][8 nt], rows = wave*32..
    f32x4 s_acc[2][8];
#pragma unroll
    for (int mi = 0; mi < 2; ++mi)
#pragma unroll
      for (int nt = 0; nt < 8; ++nt) s_acc[mi][nt] = zero;
#pragma unroll
    for (int ks = 0; ks < 2; ++ks) {
      short8 a0 = *(const short8*)(&Qs[(wave * 32 + l16) * 72 + ks * 32 + q4 * 8]);
      short8 a1 = *(const short8*)(&Qs[(wave * 32 + 16 + l16) * 72 + ks * 32 + q4 * 8]);
#pragma unroll
      for (int nt = 0; nt < 8; ++nt) {
        short8 bk = *(const short8*)(&Ks[(nt * 16 + l16) * 72 + ks * 32 + q4 * 8]);
        s_acc[0][nt] = __builtin_amdgcn_mfma_f32_16x16x32_bf16(a0, bk, s_acc[0][nt], 0, 0, 0);
        s_acc[1][nt] = __builtin_amdgcn_mfma_f32_16x16x32_bf16(a1, bk, s_acc[1][nt], 0, 0, 0);
      }
    }

    // causal mask on diagonal tile
    if (st == qt) {
#pragma unroll
      for (int mi = 0; mi < 2; ++mi)
#pragma unroll
        for (int r = 0; r < 4; ++r) {
          int t_g = qt * 128 + wave * 32 + mi * 16 + q4 * 4 + r;
#pragma unroll
          for (int nt = 0; nt < 8; ++nt) {
            int s_g = st * 128 + nt * 16 + l16;
            if (s_g > t_g) s_acc[mi][nt][r] = -3.0e38f;
          }
        }
    }

    // online softmax (per-row state lives in the 16-lane quad group)
#pragma unroll
    for (int mi = 0; mi < 2; ++mi)
#pragma unroll
      for (int r = 0; r < 4; ++r) {
        float mx = -3.0e38f;
#pragma unroll
        for (int nt = 0; nt < 8; ++nt) mx = fmaxf(mx, s_acc[mi][nt][r]);
#pragma unroll
        for (int off = 1; off < 16; off <<= 1) mx = fmaxf(mx, __shfl_xor(mx, off, 64));
        float m_new = fmaxf(m_st[mi][r], mx);
        float alpha = exp2f((m_st[mi][r] - m_new) * LOG2E);
        m_st[mi][r] = m_new;
        float rsum = 0.f;
#pragma unroll
        for (int nt = 0; nt < 8; ++nt) {
          float e = exp2f((s_acc[mi][nt][r] - m_new) * LOG2E);
          s_acc[mi][nt][r] = e;
          rsum += e;
        }
#pragma unroll
        for (int off = 1; off < 16; off <<= 1) rsum += __shfl_xor(rsum, off, 64);
        l_st[mi][r] = l_st[mi][r] * alpha + rsum;
#pragma unroll
        for (int nd = 0; nd < 4; ++nd) {
          o_acc[mi][nd][0] = (r == 0) ? o_acc[mi][nd][0] * alpha : o_acc[mi][nd][0];
        }
        // scale all regs of this row: row r maps to reg r
#pragma unroll
        for (int nd = 0; nd < 4; ++nd) o_acc[mi][nd][r] *= alpha;
      }

    // PV: P [32][128] chunked into 4x [32][32] via per-wave LDS round-trip
#pragma unroll
    for (int sc = 0; sc < 4; ++sc) {
#pragma unroll
      for (int mi = 0; mi < 2; ++mi)
#pragma unroll
        for (int jn = 0; jn < 2; ++jn) {
          int nt = sc * 2 + jn;
#pragma unroll
          for (int r = 0; r < 4; ++r)
            Ps[wave][(mi * 16 + q4 * 4 + r) * 40 + jn * 16 + l16] =
                f2bf(s_acc[mi][nt][r]);
        }
      // wave-private LDS: enforce write->read order without a block barrier
      asm volatile("s_waitcnt lgkmcnt(0)" ::: "memory");
#pragma unroll
      for (int mi = 0; mi < 2; ++mi) {
        short8 ap = *(const short8*)(&Ps[wave][(mi * 16 + l16) * 40 + q4 * 8]);
#pragma unroll
        for (int nd = 0; nd < 4; ++nd) {
          short8 bv = *(const short8*)(&Vts[(nd * 16 + l16) * 136 + sc * 32 + q4 * 8]);
          o_acc[mi][nd] = __builtin_amdgcn_mfma_f32_16x16x32_bf16(ap, bv, o_acc[mi][nd], 0, 0, 0);
        }
      }
    }
  }

  // write O / l to out fp32 [B][T][C]
  int b = bh >> 4, h = bh & 15;
#pragma unroll
  for (int mi = 0; mi < 2; ++mi)
#pragma unroll
    for (int r = 0; r < 4; ++r) {
      int t = qt * 128 + wave * 32 + mi * 16 + q4 * 4 + r;
      float inv = 1.0f / l_st[mi][r];
#pragma unroll
      for (int nd = 0; nd < 4; ++nd) {
        int c = h * 64 + nd * 16 + l16;
        out[((size_t)b * 2048 + t) * 1024 + c] = o_acc[mi][nd][r] * inv;
      }
    }
}

extern "C" void kernel_launch(void* const* d_in, const int* in_sizes, int n_in,
                              void* d_out, int out_size, void* d_ws, size_t ws_size,
                              hipStream_t stream) {
  const float* x = (const float*)d_in[0];     // [4,2048,1024]
  const float* W = (const float*)d_in[1];     // [3072,1024]
  const float* bias = (const float*)d_in[2];  // [3072]
  float* out = (float*)d_out;

  char* ws = (char*)d_ws;
  unsigned short* xb = (unsigned short*)(ws);
  unsigned short* wb = (unsigned short*)(ws + 16777216);
  unsigned short* qb = (unsigned short*)(ws + 23068672);
  unsigned short* kb = (unsigned short*)(ws + 39845888);
  unsigned short* vtb = (unsigned short*)(ws + 56623104);

  hipLaunchKernelGGL(cvt_bf16, dim3(4096), dim3(256), 0, stream, x, xb, 1048576);
  hipLaunchKernelGGL(cvt_bf16, dim3(1536), dim3(256), 0, stream, W, wb, 393216);
  hipLaunchKernelGGL(qkv_gemm, dim3(64, 24), dim3(256), 0, stream, xb, wb, bias,
                     qb, kb, vtb);
  hipLaunchKernelGGL(flash_attn, dim3(16, 64), dim3(256), 0, stream, qb, kb, vtb, out);
}

// Round 3
// 260.789 us; speedup vs baseline: 1.8375x; 1.8375x over previous
//
#include <hip/hip_runtime.h>

// Attention: qkv = x @ W^T + b ; causal MHA ; B=4 T=2048 C=1024 H=16 D=64
// R3: transposed flash (S^T = K Q^T, O^T = V^T P^T) with PV via
// v_mfma_f32_16x16x16_bf16: the 16x16 C/D layout (col=l16,row=q4*4+reg) IS the
// 16x16x16 B-operand layout (B[n=l16][k=q4*4+i]) -> S^T accumulators feed PV
// directly after an in-register f32->bf16 pack. No cross-lane transform at all.
//  - K-tile 64, XOR-swizzled 16 KB LDS, global_load_lds width-16 staging
//  - each block does Q-tiles {bx, 15-bx}: constant work -> perfect balance
//  - log2e folded into q scale (GEMM epilogue): P = exp2(S - m)
// Workspace layout (>= 72 MB):
//   xb @0 x bf16 [8192][1024] | wb @16M W bf16 [3072][1024]
//   qb @22M q bf16 [B][H][T][D] scaled 0.125*log2e | kb @38M | vtb @54M v^T [B][H][D][T]

typedef __attribute__((ext_vector_type(8))) short short8;
typedef __attribute__((ext_vector_type(4))) short s16x4;
typedef __attribute__((ext_vector_type(4))) float f32x4;

#define AS1 __attribute__((address_space(1)))
#define AS3 __attribute__((address_space(3)))

__device__ __forceinline__ unsigned short f2bf(float f) {
  unsigned int u = __float_as_uint(f);
  u += 0x7fffu + ((u >> 16) & 1u);
  return (unsigned short)(u >> 16);
}

// pack two fp32 -> bf16x2 dword (lo in low 16)
__device__ __forceinline__ unsigned int pack_bf16(float lo, float hi) {
  return __builtin_amdgcn_perm(__float_as_uint(hi) + 0x8000u,
                               __float_as_uint(lo) + 0x8000u, 0x07060302u);
}

// async 16B/lane global->LDS; LDS dest = wave-uniform base + lane*16
__device__ __forceinline__ void async_copy16(const unsigned short* g, unsigned short* l) {
  const AS1 unsigned char* gp = (const AS1 unsigned char*)(unsigned long long)(uintptr_t)g;
  AS3 unsigned char* lp = (AS3 unsigned char*)(unsigned int)(uintptr_t)l;
  __builtin_amdgcn_global_load_lds((const AS1 void*)gp, (AS3 void*)lp, 16, 0, 0);
}

// ---------------- fp32 -> bf16 bulk convert ----------------
__global__ __launch_bounds__(256) void cvt_bf16(const float* __restrict__ in,
                                                unsigned short* __restrict__ out,
                                                int n8) {
  int i = blockIdx.x * 256 + threadIdx.x;
  if (i >= n8) return;
  const float4* p = (const float4*)in + (size_t)i * 2;
  float4 a = p[0], b = p[1];
  uint4 o;
  o.x = (unsigned)f2bf(a.x) | ((unsigned)f2bf(a.y) << 16);
  o.y = (unsigned)f2bf(a.z) | ((unsigned)f2bf(a.w) << 16);
  o.z = (unsigned)f2bf(b.x) | ((unsigned)f2bf(b.y) << 16);
  o.w = (unsigned)f2bf(b.z) | ((unsigned)f2bf(b.w) << 16);
  *(uint4*)(out + (size_t)i * 8) = o;
}

// ---------------- QKV projection GEMM (passed in R1; unchanged) ----------------
__global__ __launch_bounds__(256) void qkv_gemm(const unsigned short* __restrict__ A,
                                                const unsigned short* __restrict__ Bw,
                                                const float* __restrict__ bias,
                                                unsigned short* __restrict__ qb,
                                                unsigned short* __restrict__ kb,
                                                unsigned short* __restrict__ vtb) {
  const int K = 1024;
  __shared__ unsigned short As[128 * 40];
  __shared__ unsigned short Bs[128 * 40];
  int tid = threadIdx.x;
  int wave = tid >> 6, lane = tid & 63;
  int q4 = lane >> 4, l16 = lane & 15;
  int bm = blockIdx.x, bn = blockIdx.y;
  int wm = (wave & 1) * 64, wn = (wave >> 1) * 64;

  f32x4 zero = {0.f, 0.f, 0.f, 0.f};
  f32x4 acc[4][4];
#pragma unroll
  for (int i = 0; i < 4; ++i)
#pragma unroll
    for (int j = 0; j < 4; ++j) acc[i][j] = zero;

  const unsigned short* Arow = A + (size_t)(bm * 128) * K;
  const unsigned short* Brow = Bw + (size_t)(bn * 128) * K;

  for (int kt = 0; kt < 32; ++kt) {
    __syncthreads();
    int kbase = kt * 32;
#pragma unroll
    for (int it = 0; it < 2; ++it) {
      int cn = it * 256 + tid;
      int row = cn >> 2, cc = cn & 3;
      uint4 va = *(const uint4*)(Arow + (size_t)row * K + kbase + cc * 8);
      *(uint4*)(&As[row * 40 + cc * 8]) = va;
      uint4 vb = *(const uint4*)(Brow + (size_t)row * K + kbase + cc * 8);
      *(uint4*)(&Bs[row * 40 + cc * 8]) = vb;
    }
    __syncthreads();
    short8 af[4], bf[4];
#pragma unroll
    for (int i = 0; i < 4; ++i)
      af[i] = *(const short8*)(&As[(wm + i * 16 + l16) * 40 + q4 * 8]);
#pragma unroll
    for (int j = 0; j < 4; ++j)
      bf[j] = *(const short8*)(&Bs[(wn + j * 16 + l16) * 40 + q4 * 8]);
#pragma unroll
    for (int i = 0; i < 4; ++i)
#pragma unroll
      for (int j = 0; j < 4; ++j)
        acc[i][j] = __builtin_amdgcn_mfma_f32_16x16x32_bf16(af[i], bf[j], acc[i][j], 0, 0, 0);
  }

  // q scale folds 1/sqrt(64) AND log2e
  const float QSCALE = 0.18033688011112042f;
  int rowbase = bm * 128 + wm;
  int colbase = bn * 128 + wn;
#pragma unroll
  for (int j = 0; j < 4; ++j) {
    int o = colbase + j * 16 + l16;
    float bv = bias[o];
#pragma unroll
    for (int i = 0; i < 4; ++i) {
      int r0 = rowbase + i * 16 + q4 * 4;
      if (o < 1024) {
        int h = o >> 6, d = o & 63;
#pragma unroll
        for (int r = 0; r < 4; ++r) {
          int m = r0 + r;
          int b = m >> 11, t = m & 2047;
          qb[((((size_t)b * 16 + h) * 2048 + t) << 6) + d] = f2bf((acc[i][j][r] + bv) * QSCALE);
        }
      } else if (o < 2048) {
        int o2 = o - 1024;
        int h = o2 >> 6, d = o2 & 63;
#pragma unroll
        for (int r = 0; r < 4; ++r) {
          int m = r0 + r;
          int b = m >> 11, t = m & 2047;
          kb[((((size_t)b * 16 + h) * 2048 + t) << 6) + d] = f2bf(acc[i][j][r] + bv);
        }
      } else {
        int o3 = o - 2048;
        int h = o3 >> 6, d = o3 & 63;
        int b = r0 >> 11, t = r0 & 2047;
        ushort4 pk;
        pk.x = f2bf(acc[i][j][0] + bv);
        pk.y = f2bf(acc[i][j][1] + bv);
        pk.z = f2bf(acc[i][j][2] + bv);
        pk.w = f2bf(acc[i][j][3] + bv);
        *(ushort4*)(&vtb[((((size_t)b * 16 + h) * 64 + d) << 11) + t]) = pk;
      }
    }
  }
}

// ---------------- Flash attention, transposed orientation ----------------
// Grid (8, 64), 256 thr. Block does Q-tiles bx and 15-bx. K-subtile = 64.
__global__ __launch_bounds__(256, 3) void flash_attn(const unsigned short* __restrict__ qb,
                                                     const unsigned short* __restrict__ kb,
                                                     const unsigned short* __restrict__ vtb,
                                                     float* __restrict__ out) {
  __shared__ unsigned short Ks[64 * 64];   // [s][group ^ (s&7)] 16B-group swizzle
  __shared__ unsigned short Vts[64 * 64];  // [d][group ^ (d&7)]

  const int tid = threadIdx.x;
  const int wave = tid >> 6, lane = tid & 63;
  const int q4 = lane >> 4, l16 = lane & 15;
  const int bx = blockIdx.x, bh = blockIdx.y;
  const int b = bh >> 4, h = bh & 15;

  const unsigned short* Qg = qb + (size_t)bh * (2048 * 64);
  const unsigned short* Kg = kb + (size_t)bh * (2048 * 64);
  const unsigned short* Vg = vtb + (size_t)bh * (64 * 2048);

  // staging: wave stages 16 rows (2 insts x 8 rows), 16B/lane; swizzle applied
  // on the GLOBAL side (LDS placement is fixed at base + lane*16)
  const int srow = (wave << 4) + (lane >> 3);
  const int sg = (lane & 7) ^ (srow & 7);
  const int koff = srow * 64 + sg * 8;
  const int voff = srow * 2048 + sg * 8;
  unsigned short* lk = Ks + wave * 1024;
  unsigned short* lv = Vts + wave * 1024;

  for (int pass = 0; pass < 2; ++pass) {
    const int qt = pass ? 15 - bx : bx;
    const int t0w = qt * 128 + wave * 32;

    short8 qf[2][2];
#pragma unroll
    for (int mi = 0; mi < 2; ++mi)
#pragma unroll
      for (int ks = 0; ks < 2; ++ks)
        qf[mi][ks] = *(const short8*)(Qg + (size_t)(t0w + mi * 16 + l16) * 64 + ks * 32 + q4 * 8);

    f32x4 zero = {0.f, 0.f, 0.f, 0.f};
    f32x4 oT[4][2];
#pragma unroll
    for (int nd = 0; nd < 4; ++nd) {
      oT[nd][0] = zero;
      oT[nd][1] = zero;
    }
    float m_s[2] = {-3.0e38f, -3.0e38f};
    float l_s[2] = {0.f, 0.f};

    const int nst = 2 * qt + 2;
    for (int st = 0; st < nst; ++st) {
      __syncthreads();  // prior iter's LDS reads done
      const unsigned short* kgp = Kg + st * 4096 + koff;
      const unsigned short* vgp = Vg + st * 64 + voff;
      async_copy16(kgp, lk);
      async_copy16(kgp + 512, lk + 512);
      async_copy16(vgp, lv);
      async_copy16(vgp + 16384, lv + 512);
      __syncthreads();  // vmcnt drained by compiler before barrier

      if (st * 64 > t0w + 31) continue;  // tile fully masked for this wave

      // S^T = K Q^T : sT[mi][ns][r] = S[s=st*64+ns*16+q4*4+r][t=t0w+mi*16+l16]
      f32x4 sT[2][4];
#pragma unroll
      for (int ns = 0; ns < 4; ++ns) {
        sT[0][ns] = zero;
        sT[1][ns] = zero;
      }
#pragma unroll
      for (int ks = 0; ks < 2; ++ks)
#pragma unroll
        for (int ns = 0; ns < 4; ++ns) {
          int sr = ns * 16 + l16;
          short8 kf = *(const short8*)(&Ks[sr * 64 + (((ks * 4 + q4) ^ (sr & 7)) << 3)]);
          sT[0][ns] = __builtin_amdgcn_mfma_f32_16x16x32_bf16(kf, qf[0][ks], sT[0][ns], 0, 0, 0);
          sT[1][ns] = __builtin_amdgcn_mfma_f32_16x16x32_bf16(kf, qf[1][ks], sT[1][ns], 0, 0, 0);
        }

      // causal mask (only on tiles crossing the diagonal)
      if (st * 64 + 63 > t0w) {
#pragma unroll
        for (int mi = 0; mi < 2; ++mi) {
          int tg = t0w + mi * 16 + l16;
#pragma unroll
          for (int ns = 0; ns < 4; ++ns)
#pragma unroll
            for (int r = 0; r < 4; ++r)
              if (st * 64 + ns * 16 + q4 * 4 + r > tg) sT[mi][ns][r] = -3.0e38f;
        }
      }

      // online softmax: rows on l16, reduce across quads (2 shuffles)
#pragma unroll
      for (int mi = 0; mi < 2; ++mi) {
        float mx = -3.0e38f;
#pragma unroll
        for (int ns = 0; ns < 4; ++ns)
#pragma unroll
          for (int r = 0; r < 4; ++r) mx = fmaxf(mx, sT[mi][ns][r]);
        mx = fmaxf(mx, __shfl_xor(mx, 16, 64));
        mx = fmaxf(mx, __shfl_xor(mx, 32, 64));
        float mnew = fmaxf(m_s[mi], mx);
        float alpha = exp2f(m_s[mi] - mnew);
        m_s[mi] = mnew;
        float rsum = 0.f;
#pragma unroll
        for (int ns = 0; ns < 4; ++ns)
#pragma unroll
          for (int r = 0; r < 4; ++r) {
            float e = exp2f(sT[mi][ns][r] - mnew);
            sT[mi][ns][r] = e;
            rsum += e;
          }
        rsum += __shfl_xor(rsum, 16, 64);
        rsum += __shfl_xor(rsum, 32, 64);
        l_s[mi] = l_s[mi] * alpha + rsum;
#pragma unroll
        for (int nd = 0; nd < 4; ++nd) oT[nd][mi] *= alpha;
      }

      // O^T += V^T P^T via 16x16x16 MFMA: S^T C-layout == B-operand layout.
      // P^T B-frag for s-chunk ns is just sT[mi][ns] packed to bf16.
#pragma unroll
      for (int ns = 0; ns < 4; ++ns) {
        s16x4 pf[2];
#pragma unroll
        for (int mi = 0; mi < 2; ++mi) {
          union { unsigned int u[2]; s16x4 s4; } pu;
          pu.u[0] = pack_bf16(sT[mi][ns][0], sT[mi][ns][1]);
          pu.u[1] = pack_bf16(sT[mi][ns][2], sT[mi][ns][3]);
          pf[mi] = pu.s4;
        }
#pragma unroll
        for (int nd = 0; nd < 4; ++nd) {
          int dr = nd * 16 + l16;
          // V^T A-frag: A[m=d][k=q4*4+i], s_local = ns*16 + q4*4 + i
          s16x4 vf = *(const s16x4*)(&Vts[dr * 64 +
                       ((((ns << 1) + (q4 >> 1)) ^ (dr & 7)) << 3) + ((q4 & 1) << 2)]);
          oT[nd][0] = __builtin_amdgcn_mfma_f32_16x16x16bf16_1k(vf, pf[0], oT[nd][0], 0, 0, 0);
          oT[nd][1] = __builtin_amdgcn_mfma_f32_16x16x16bf16_1k(vf, pf[1], oT[nd][1], 0, 0, 0);
        }
      }
    }

    // epilogue: out[b][t][h*64 + d] = O^T[d][t] / l
#pragma unroll
    for (int mi = 0; mi < 2; ++mi) {
      float inv = 1.0f / l_s[mi];
      int t = t0w + mi * 16 + l16;
      float* op = out + (size_t)(b * 2048 + t) * 1024 + h * 64 + q4 * 4;
#pragma unroll
      for (int nd = 0; nd < 4; ++nd) {
        float4 o4 = {oT[nd][mi][0] * inv, oT[nd][mi][1] * inv, oT[nd][mi][2] * inv,
                     oT[nd][mi][3] * inv};
        *(float4*)(op + nd * 16) = o4;
      }
    }
  }
}

extern "C" void kernel_launch(void* const* d_in, const int* in_sizes, int n_in,
                              void* d_out, int out_size, void* d_ws, size_t ws_size,
                              hipStream_t stream) {
  const float* x = (const float*)d_in[0];
  const float* W = (const float*)d_in[1];
  const float* bias = (const float*)d_in[2];
  float* out = (float*)d_out;

  char* ws = (char*)d_ws;
  unsigned short* xb = (unsigned short*)(ws);
  unsigned short* wb = (unsigned short*)(ws + 16777216);
  unsigned short* qb = (unsigned short*)(ws + 23068672);
  unsigned short* kb = (unsigned short*)(ws + 39845888);
  unsigned short* vtb = (unsigned short*)(ws + 56623104);

  hipLaunchKernelGGL(cvt_bf16, dim3(4096), dim3(256), 0, stream, x, xb, 1048576);
  hipLaunchKernelGGL(cvt_bf16, dim3(1536), dim3(256), 0, stream, W, wb, 393216);
  hipLaunchKernelGGL(qkv_gemm, dim3(64, 24), dim3(256), 0, stream, xb, wb, bias,
                     qb, kb, vtb);
  hipLaunchKernelGGL(flash_attn, dim3(8, 64), dim3(256), 0, stream, qb, kb, vtb, out);
}

// Round 4
// 234.452 us; speedup vs baseline: 2.0439x; 1.1123x over previous
//
#include <hip/hip_runtime.h>

// Attention: qkv = x @ W^T + b ; causal MHA ; B=4 T=2048 C=1024 H=16 D=64
// R4: (1) flash Q-tile 64, grid (16,64)=1024 blocks (4/CU), pair {bx,31-bx};
//     (2) qkv_gemm m97-style: global_load_lds width-16 staging, BK=64,
//         XOR swizzle applied on the GLOBAL side (LDS dest is lane-contiguous).
// Transposed flash retained from R3: S^T = K Q^T; O^T = V^T P^T via
// v_mfma_f32_16x16x16_bf16 (S^T C-layout == its B-operand layout; no shuffle).
// Workspace (>= 72 MB): xb@0 [8192][1024] | wb@16M [3072][1024]
//   qb@22M q bf16 [B][H][T][D] *0.125*log2e | kb@38M | vtb@54M v^T [B][H][D][T]

typedef __attribute__((ext_vector_type(8))) short short8;
typedef __attribute__((ext_vector_type(4))) short s16x4;
typedef __attribute__((ext_vector_type(4))) float f32x4;

#define AS1 __attribute__((address_space(1)))
#define AS3 __attribute__((address_space(3)))

__device__ __forceinline__ unsigned short f2bf(float f) {
  unsigned int u = __float_as_uint(f);
  u += 0x7fffu + ((u >> 16) & 1u);
  return (unsigned short)(u >> 16);
}

__device__ __forceinline__ unsigned int pack_bf16(float lo, float hi) {
  return __builtin_amdgcn_perm(__float_as_uint(hi) + 0x8000u,
                               __float_as_uint(lo) + 0x8000u, 0x07060302u);
}

// async 16B/lane global->LDS; LDS dest = wave-uniform base + lane*16
__device__ __forceinline__ void async_copy16(const unsigned short* g, unsigned short* l) {
  const AS1 unsigned char* gp = (const AS1 unsigned char*)(unsigned long long)(uintptr_t)g;
  AS3 unsigned char* lp = (AS3 unsigned char*)(unsigned int)(uintptr_t)l;
  __builtin_amdgcn_global_load_lds((const AS1 void*)gp, (AS3 void*)lp, 16, 0, 0);
}

// ---------------- fp32 -> bf16 bulk convert ----------------
__global__ __launch_bounds__(256) void cvt_bf16(const float* __restrict__ in,
                                                unsigned short* __restrict__ out,
                                                int n8) {
  int i = blockIdx.x * 256 + threadIdx.x;
  if (i >= n8) return;
  const float4* p = (const float4*)in + (size_t)i * 2;
  float4 a = p[0], b = p[1];
  uint4 o;
  o.x = (unsigned)f2bf(a.x) | ((unsigned)f2bf(a.y) << 16);
  o.y = (unsigned)f2bf(a.z) | ((unsigned)f2bf(a.w) << 16);
  o.z = (unsigned)f2bf(b.x) | ((unsigned)f2bf(b.y) << 16);
  o.w = (unsigned)f2bf(b.z) | ((unsigned)f2bf(b.w) << 16);
  *(uint4*)(out + (size_t)i * 8) = o;
}

// ---------------- QKV projection GEMM, global_load_lds staging ----------------
// 128x128 tile, BK=64, 4 waves 2x2, wave 64x64 = 4x4 16x16x32 MFMA x 2 ks.
// LDS [row][64] shorts; global group g lives at LDS pos g ^ (row&7).
__global__ __launch_bounds__(256) void qkv_gemm(const unsigned short* __restrict__ A,
                                                const unsigned short* __restrict__ Bw,
                                                const float* __restrict__ bias,
                                                unsigned short* __restrict__ qb,
                                                unsigned short* __restrict__ kb,
                                                unsigned short* __restrict__ vtb) {
  const int K = 1024;
  __shared__ unsigned short As[128 * 64];
  __shared__ unsigned short Bs[128 * 64];
  int tid = threadIdx.x;
  int wave = tid >> 6, lane = tid & 63;
  int q4 = lane >> 4, l16 = lane & 15;
  int bm = blockIdx.x, bn = blockIdx.y;
  int wm = (wave & 1) * 64, wn = (wave >> 1) * 64;

  f32x4 zero = {0.f, 0.f, 0.f, 0.f};
  f32x4 acc[4][4];
#pragma unroll
  for (int i = 0; i < 4; ++i)
#pragma unroll
    for (int j = 0; j < 4; ++j) acc[i][j] = zero;

  const unsigned short* Ab = A + (size_t)(bm * 128) * K;
  const unsigned short* Bb = Bw + (size_t)(bn * 128) * K;

  // staging geometry: per inst a wave stages 8 rows (8 lanes x 16B per row)
  const int srow0 = wave * 8 + (lane >> 3);           // row within 32-row chunk... (wave*8 + r8)
  unsigned short* lA0 = As + (wave * 8) * 64;         // wave-uniform LDS base
  unsigned short* lB0 = Bs + (wave * 8) * 64;

  for (int kt = 0; kt < 16; ++kt) {
    __syncthreads();
    int kbase = kt * 64;
#pragma unroll
    for (int inst = 0; inst < 4; ++inst) {
      int row = inst * 32 + srow0;
      int g = (lane & 7) ^ (row & 7);
      const unsigned short* ga = Ab + (size_t)row * K + kbase + g * 8;
      const unsigned short* gb = Bb + (size_t)row * K + kbase + g * 8;
      async_copy16(ga, lA0 + inst * 2048);
      async_copy16(gb, lB0 + inst * 2048);
    }
    __syncthreads();
#pragma unroll
    for (int ks = 0; ks < 2; ++ks) {
      short8 af[4], bf[4];
#pragma unroll
      for (int i = 0; i < 4; ++i)
        af[i] = *(const short8*)(&As[(wm + i * 16 + l16) * 64 +
                                     (((ks * 4 + q4) ^ (l16 & 7)) << 3)]);
#pragma unroll
      for (int j = 0; j < 4; ++j)
        bf[j] = *(const short8*)(&Bs[(wn + j * 16 + l16) * 64 +
                                     (((ks * 4 + q4) ^ (l16 & 7)) << 3)]);
#pragma unroll
      for (int i = 0; i < 4; ++i)
#pragma unroll
        for (int j = 0; j < 4; ++j)
          acc[i][j] = __builtin_amdgcn_mfma_f32_16x16x32_bf16(af[i], bf[j], acc[i][j], 0, 0, 0);
    }
  }

  // epilogue (verified R1): +bias; q scaled by 0.125*log2e; v stored transposed
  const float QSCALE = 0.18033688011112042f;
  int rowbase = bm * 128 + wm;
  int colbase = bn * 128 + wn;
#pragma unroll
  for (int j = 0; j < 4; ++j) {
    int o = colbase + j * 16 + l16;
    float bv = bias[o];
#pragma unroll
    for (int i = 0; i < 4; ++i) {
      int r0 = rowbase + i * 16 + q4 * 4;
      if (o < 1024) {
        int h = o >> 6, d = o & 63;
#pragma unroll
        for (int r = 0; r < 4; ++r) {
          int m = r0 + r;
          int b = m >> 11, t = m & 2047;
          qb[((((size_t)b * 16 + h) * 2048 + t) << 6) + d] = f2bf((acc[i][j][r] + bv) * QSCALE);
        }
      } else if (o < 2048) {
        int o2 = o - 1024;
        int h = o2 >> 6, d = o2 & 63;
#pragma unroll
        for (int r = 0; r < 4; ++r) {
          int m = r0 + r;
          int b = m >> 11, t = m & 2047;
          kb[((((size_t)b * 16 + h) * 2048 + t) << 6) + d] = f2bf(acc[i][j][r] + bv);
        }
      } else {
        int o3 = o - 2048;
        int h = o3 >> 6, d = o3 & 63;
        int b = r0 >> 11, t = r0 & 2047;
        ushort4 pk;
        pk.x = f2bf(acc[i][j][0] + bv);
        pk.y = f2bf(acc[i][j][1] + bv);
        pk.z = f2bf(acc[i][j][2] + bv);
        pk.w = f2bf(acc[i][j][3] + bv);
        *(ushort4*)(&vtb[((((size_t)b * 16 + h) * 64 + d) << 11) + t]) = pk;
      }
    }
  }
}

// ---------------- Flash attention, transposed, Q-tile 64 ----------------
// Grid (16, 64), 256 thr. Block does Q-tiles bx and 31-bx (33 K-tiles const).
// Wave owns 16 q-rows: t = qt*64 + wave*16 + l16. K-subtile = 64.
__global__ __launch_bounds__(256, 4) void flash_attn(const unsigned short* __restrict__ qb,
                                                     const unsigned short* __restrict__ kb,
                                                     const unsigned short* __restrict__ vtb,
                                                     float* __restrict__ out) {
  __shared__ unsigned short Ks[64 * 64];   // [s][group ^ (s&7)]
  __shared__ unsigned short Vts[64 * 64];  // [d][group ^ (d&7)]

  const int tid = threadIdx.x;
  const int wave = tid >> 6, lane = tid & 63;
  const int q4 = lane >> 4, l16 = lane & 15;
  const int bx = blockIdx.x, bh = blockIdx.y;
  const int b = bh >> 4, h = bh & 15;

  const unsigned short* Qg = qb + (size_t)bh * (2048 * 64);
  const unsigned short* Kg = kb + (size_t)bh * (2048 * 64);
  const unsigned short* Vg = vtb + (size_t)bh * (64 * 2048);

  const int srow = (wave << 4) + (lane >> 3);
  const int sg = (lane & 7) ^ (srow & 7);
  const int koff = srow * 64 + sg * 8;
  const int voff = srow * 2048 + sg * 8;
  unsigned short* lk = Ks + wave * 1024;
  unsigned short* lv = Vts + wave * 1024;

  for (int pass = 0; pass < 2; ++pass) {
    const int qt = pass ? 31 - bx : bx;
    const int t0w = qt * 64 + wave * 16;

    short8 qf[2];
#pragma unroll
    for (int ks = 0; ks < 2; ++ks)
      qf[ks] = *(const short8*)(Qg + (size_t)(t0w + l16) * 64 + ks * 32 + q4 * 8);

    f32x4 zero = {0.f, 0.f, 0.f, 0.f};
    f32x4 oT[4];
#pragma unroll
    for (int nd = 0; nd < 4; ++nd) oT[nd] = zero;
    float m_s = -3.0e38f, l_s = 0.f;

    const int nst = qt + 1;
    for (int st = 0; st < nst; ++st) {
      __syncthreads();  // prior iter's LDS reads done
      const unsigned short* kgp = Kg + st * 4096 + koff;
      const unsigned short* vgp = Vg + st * 64 + voff;
      async_copy16(kgp, lk);
      async_copy16(kgp + 512, lk + 512);
      async_copy16(vgp, lv);
      async_copy16(vgp + 16384, lv + 512);
      __syncthreads();  // vmcnt drained by compiler before barrier

      if (st * 64 > t0w + 15) continue;  // fully masked for this wave

      // S^T = K Q^T : sT[ns][r] = S[s=st*64+ns*16+q4*4+r][t=t0w+l16]
      f32x4 sT[4];
#pragma unroll
      for (int ns = 0; ns < 4; ++ns) sT[ns] = zero;
#pragma unroll
      for (int ks = 0; ks < 2; ++ks)
#pragma unroll
        for (int ns = 0; ns < 4; ++ns) {
          int sr = ns * 16 + l16;
          short8 kf = *(const short8*)(&Ks[sr * 64 + (((ks * 4 + q4) ^ (sr & 7)) << 3)]);
          sT[ns] = __builtin_amdgcn_mfma_f32_16x16x32_bf16(kf, qf[ks], sT[ns], 0, 0, 0);
        }

      // causal mask on diagonal-crossing tiles
      if (st * 64 + 63 > t0w) {
        int tg = t0w + l16;
#pragma unroll
        for (int ns = 0; ns < 4; ++ns)
#pragma unroll
          for (int r = 0; r < 4; ++r)
            if (st * 64 + ns * 16 + q4 * 4 + r > tg) sT[ns][r] = -3.0e38f;
      }

      // online softmax: row on l16, reduce across quads (2 shuffles)
      float mx = -3.0e38f;
#pragma unroll
      for (int ns = 0; ns < 4; ++ns)
#pragma unroll
        for (int r = 0; r < 4; ++r) mx = fmaxf(mx, sT[ns][r]);
      mx = fmaxf(mx, __shfl_xor(mx, 16, 64));
      mx = fmaxf(mx, __shfl_xor(mx, 32, 64));
      float mnew = fmaxf(m_s, mx);
      float alpha = exp2f(m_s - mnew);
      m_s = mnew;
      float rsum = 0.f;
#pragma unroll
      for (int ns = 0; ns < 4; ++ns)
#pragma unroll
        for (int r = 0; r < 4; ++r) {
          float e = exp2f(sT[ns][r] - mnew);
          sT[ns][r] = e;
          rsum += e;
        }
      rsum += __shfl_xor(rsum, 16, 64);
      rsum += __shfl_xor(rsum, 32, 64);
      l_s = l_s * alpha + rsum;
#pragma unroll
      for (int nd = 0; nd < 4; ++nd) oT[nd] *= alpha;

      // O^T += V^T P^T via 16x16x16: S^T C-layout == B-operand layout
#pragma unroll
      for (int ns = 0; ns < 4; ++ns) {
        union { unsigned int u[2]; s16x4 s4; } pu;
        pu.u[0] = pack_bf16(sT[ns][0], sT[ns][1]);
        pu.u[1] = pack_bf16(sT[ns][2], sT[ns][3]);
#pragma unroll
        for (int nd = 0; nd < 4; ++nd) {
          int dr = nd * 16 + l16;
          s16x4 vf = *(const s16x4*)(&Vts[dr * 64 +
                       ((((ns << 1) + (q4 >> 1)) ^ (dr & 7)) << 3) + ((q4 & 1) << 2)]);
          oT[nd] = __builtin_amdgcn_mfma_f32_16x16x16bf16_1k(vf, pu.s4, oT[nd], 0, 0, 0);
        }
      }
    }

    // epilogue: out[b][t = t0w+l16][h*64 + d], d = nd*16 + q4*4 + r
    float inv = 1.0f / l_s;
    int t = t0w + l16;
    float* op = out + (size_t)(b * 2048 + t) * 1024 + h * 64 + q4 * 4;
#pragma unroll
    for (int nd = 0; nd < 4; ++nd) {
      float4 o4 = {oT[nd][0] * inv, oT[nd][1] * inv, oT[nd][2] * inv, oT[nd][3] * inv};
      *(float4*)(op + nd * 16) = o4;
    }
  }
}

extern "C" void kernel_launch(void* const* d_in, const int* in_sizes, int n_in,
                              void* d_out, int out_size, void* d_ws, size_t ws_size,
                              hipStream_t stream) {
  const float* x = (const float*)d_in[0];
  const float* W = (const float*)d_in[1];
  const float* bias = (const float*)d_in[2];
  float* out = (float*)d_out;

  char* ws = (char*)d_ws;
  unsigned short* xb = (unsigned short*)(ws);
  unsigned short* wb = (unsigned short*)(ws + 16777216);
  unsigned short* qb = (unsigned short*)(ws + 23068672);
  unsigned short* kb = (unsigned short*)(ws + 39845888);
  unsigned short* vtb = (unsigned short*)(ws + 56623104);

  hipLaunchKernelGGL(cvt_bf16, dim3(4096), dim3(256), 0, stream, x, xb, 1048576);
  hipLaunchKernelGGL(cvt_bf16, dim3(1536), dim3(256), 0, stream, W, wb, 393216);
  hipLaunchKernelGGL(qkv_gemm, dim3(64, 24), dim3(256), 0, stream, xb, wb, bias,
                     qb, kb, vtb);
  hipLaunchKernelGGL(flash_attn, dim3(16, 64), dim3(256), 0, stream, qb, kb, vtb, out);
}